// Round 6
// baseline (1025.342 us; speedup 1.0000x reference)
//
#include <hip/hip_runtime.h>
#include <math.h>

// GQA: B=1, S=2048, D=128, H=32, KVH=8, unmasked softmax attention.
// d_out f32. ws use: 10.5 MB. Direct-exp softmax (|s*SCALE| < ~0.3 so no max
// subtraction needed). Round-6 fix: K-tile LDS staging covered only HALF the
// tile (8-short writes on a 16-short stride) -> QK^T ran over 64 of 128 dims.

#define SCALE 0.08838834764831843f  // 1/sqrt(128)

typedef short bf16x8 __attribute__((ext_vector_type(8)));
typedef float f32x4 __attribute__((ext_vector_type(4)));

__device__ __forceinline__ unsigned short f2b(float f) {
  union { float f; unsigned u; } x; x.f = f;
  return (unsigned short)((x.u + 0x7FFFu + ((x.u >> 16) & 1u)) >> 16);
}
__device__ __forceinline__ float b2f(unsigned short b) {
  union { unsigned u; float f; } x; x.u = ((unsigned)b) << 16;
  return x.f;
}

__global__ void cast_w(const float* __restrict__ W, unsigned short* __restrict__ Wb, int n) {
  int i = blockIdx.x * 256 + threadIdx.x;
  if (i < n) Wb[i] = f2b(W[i]);
}

// Wt[n][k] = bf16(W[k][n])
__global__ void transpose_w(const float* __restrict__ W, unsigned short* __restrict__ Wt,
                            int K, int N) {
  int idx = blockIdx.x * 256 + threadIdx.x;
  if (idx >= K * N) return;
  int n = idx / K, k = idx - n * K;
  Wt[idx] = f2b(W[(size_t)k * N + n]);
}

// C_bf16[2048,N] = Xf32[2048,128] @ W + bias  (W given transposed: Wt[n][k])
__global__ __launch_bounds__(256) void proj_gemm(const float* __restrict__ X,
                                                 const unsigned short* __restrict__ Wt,
                                                 const float* __restrict__ bias,
                                                 unsigned short* __restrict__ C, int N) {
  int n0 = blockIdx.x * 64, m0 = blockIdx.y * 64;
  int tid = threadIdx.x;
  int w = tid >> 6, l = tid & 63;
  int l16 = l & 15, g4 = l >> 4;
  int arow = m0 + w * 16 + l16;
  f32x4 acc[4];
  const f32x4 fz = {0.f, 0.f, 0.f, 0.f};
#pragma unroll
  for (int nb = 0; nb < 4; ++nb) acc[nb] = fz;
#pragma unroll
  for (int kc = 0; kc < 4; ++kc) {
    int kbase = kc * 32 + g4 * 8;
    const float* xp = X + (size_t)arow * 128 + kbase;
    bf16x8 a;
#pragma unroll
    for (int j = 0; j < 8; ++j) a[j] = (short)f2b(xp[j]);
#pragma unroll
    for (int nb = 0; nb < 4; ++nb) {
      bf16x8 b = *(const bf16x8*)(Wt + (size_t)(n0 + nb * 16 + l16) * 128 + kbase);
      acc[nb] = __builtin_amdgcn_mfma_f32_16x16x32_bf16(a, b, acc[nb], 0, 0, 0);
    }
  }
#pragma unroll
  for (int nb = 0; nb < 4; ++nb) {
    int n = n0 + nb * 16 + l16;
    float bv = bias[n];
#pragma unroll
    for (int r = 0; r < 4; ++r) {
      int mi = m0 + w * 16 + g4 * 4 + r;
      C[(size_t)mi * N + n] = f2b(acc[nb][r] + bv);
    }
  }
}

// RoPE in place on K and V (both stored as (S,1024) C-layout == (g,t,d) view-flat)
__global__ void rope_kv(unsigned short* __restrict__ kp, unsigned short* __restrict__ vp) {
  int idx = blockIdx.x * 256 + threadIdx.x;  // 8*2048*64
  int d2 = idx & 63;
  int t = (idx >> 6) & 2047;
  int g = idx >> 17;
  size_t base = ((size_t)g * 2048 + t) * 128;
  double invf = pow(10000.0, -(double)d2 / 64.0);
  float ang = (float)((double)t * invf);
  float cf = cosf(ang), sf = sinf(ang);
  float x1 = b2f(kp[base + d2]), x2 = b2f(kp[base + 64 + d2]);
  kp[base + d2] = f2b(x1 * cf - x2 * sf);
  kp[base + 64 + d2] = f2b(x2 * cf + x1 * sf);
  float y1 = b2f(vp[base + d2]), y2 = b2f(vp[base + 64 + d2]);
  vp[base + d2] = f2b(y1 * cf - y2 * sf);
  vp[base + 64 + d2] = f2b(y2 * cf + y1 * sf);
}

__global__ void init_out(const float* __restrict__ bo, float* __restrict__ out) {
  int idx = blockIdx.x * 256 + threadIdx.x;  // 2048*128
  out[idx] = bo[idx & 127];
}

__global__ void ws_marker(float* __restrict__ out) {
  out[blockIdx.x * 256 + threadIdx.x] = 12345.0f;
}

// Fused: Q-projection (2 rows of X@Wq) + attention + O@Wo[h-slice] -> atomicAdd(out)
__global__ __launch_bounds__(256) void attn_fused(const float* __restrict__ X,
                                                  const unsigned short* __restrict__ Wqb,
                                                  const float* __restrict__ bq,
                                                  const unsigned short* __restrict__ kp,
                                                  const unsigned short* __restrict__ vp,
                                                  const unsigned short* __restrict__ Wot,
                                                  float* __restrict__ out) {
  __shared__ __align__(16) unsigned short Ks[32][136];
  __shared__ __align__(16) unsigned short Vs[128][40];
  __shared__ __align__(16) unsigned short Ps[4][16][40];
  __shared__ __align__(16) unsigned short Uni[8704]; // phase0: Qc[2][4096]; epilogue: O[64][136]
  int h = blockIdx.y, g = h & 7;
  int qi0 = blockIdx.x * 64;
  int tid = threadIdx.x;
  int w = tid >> 6, l = tid & 63;
  int l16 = l & 15, g4 = l >> 4;

  // ---- phase 0: Q rows qi0..qi0+63 of head h == C rows {r0, r0+1} (view scramble) ----
  int r0 = h * 64 + (qi0 >> 5);
#pragma unroll
  for (int j = 0; j < 2; ++j) {
    const float* xrow = X + (size_t)(r0 + j) * 128;
    for (int col = tid; col < 4096; col += 256) {
      float a0 = 0.f, a1 = 0.f, a2 = 0.f, a3 = 0.f;
#pragma unroll
      for (int k = 0; k < 128; k += 4) {
        a0 += xrow[k]     * b2f(Wqb[(size_t)(k)     * 4096 + col]);
        a1 += xrow[k + 1] * b2f(Wqb[(size_t)(k + 1) * 4096 + col]);
        a2 += xrow[k + 2] * b2f(Wqb[(size_t)(k + 2) * 4096 + col]);
        a3 += xrow[k + 3] * b2f(Wqb[(size_t)(k + 3) * 4096 + col]);
      }
      Uni[j * 4096 + col] = f2b(bq[col] + ((a0 + a1) + (a2 + a3)));
    }
  }
  __syncthreads();
  bf16x8 qfrag[4];
  {
    int srow = w * 16 + l16;               // s - qi0
    int sj = srow >> 5;
    int scol = (srow & 31) * 128;
#pragma unroll
    for (int kc = 0; kc < 4; ++kc)
      qfrag[kc] = *(const bf16x8*)&Uni[sj * 4096 + scol + kc * 32 + g4 * 8];
  }

  const f32x4 fz = {0.f, 0.f, 0.f, 0.f};
  f32x4 oacc[8];
#pragma unroll
  for (int db = 0; db < 8; ++db) oacc[db] = fz;
  float lacc[4] = {0.f, 0.f, 0.f, 0.f};
  const unsigned short* kbase = kp + (size_t)g * 262144;
  const unsigned short* vbase = vp + (size_t)g * 262144;

  for (int j0 = 0; j0 < 2048; j0 += 32) {
    __syncthreads();
    {
      // K: 32 rows x 8 chunks of 16 bf16 -> TWO bf16x8 writes per thread
      // (round-6 fix: previously only the low 8 of each 16-chunk was staged)
      int r = tid >> 3, c = tid & 7;
      const unsigned short* src = kbase + (size_t)(j0 + r) * 128 + c * 16;
      *(bf16x8*)&Ks[r][c * 16]     = *(const bf16x8*)(src);
      *(bf16x8*)&Ks[r][c * 16 + 8] = *(const bf16x8*)(src + 8);
      int kv = tid >> 3, d0 = (tid & 7) * 16;  // V: row-major global -> transposed LDS
      bf16x8 v0 = *(const bf16x8*)(vbase + (size_t)(j0 + kv) * 128 + d0);
      bf16x8 v1 = *(const bf16x8*)(vbase + (size_t)(j0 + kv) * 128 + d0 + 8);
#pragma unroll
      for (int e = 0; e < 8; ++e) Vs[d0 + e][kv] = (unsigned short)v0[e];
#pragma unroll
      for (int e = 0; e < 8; ++e) Vs[d0 + 8 + e][kv] = (unsigned short)v1[e];
    }
    __syncthreads();

    f32x4 sacc[2];
    sacc[0] = fz; sacc[1] = fz;
#pragma unroll
    for (int kc = 0; kc < 4; ++kc) {
#pragma unroll
      for (int jb = 0; jb < 2; ++jb) {
        bf16x8 bfrag = *(const bf16x8*)&Ks[jb * 16 + l16][kc * 32 + g4 * 8];
        sacc[jb] = __builtin_amdgcn_mfma_f32_16x16x32_bf16(qfrag[kc], bfrag, sacc[jb], 0, 0, 0);
      }
    }
    // direct-exp softmax: p = exp(s*SCALE), no max subtraction (|s*SCALE| < 0.5)
#pragma unroll
    for (int r = 0; r < 4; ++r) {
      unsigned short u0 = f2b(expf(sacc[0][r] * SCALE));
      unsigned short u1 = f2b(expf(sacc[1][r] * SCALE));
      lacc[r] += b2f(u0) + b2f(u1);  // denominator from the STORED p (consistent)
      Ps[w][g4 * 4 + r][l16] = u0;
      Ps[w][g4 * 4 + r][16 + l16] = u1;
    }
    __syncthreads();  // Ps visible before cross-lane read
    bf16x8 pfrag = *(const bf16x8*)&Ps[w][l16][g4 * 8];
#pragma unroll
    for (int db = 0; db < 8; ++db) {
      bf16x8 vfrag = *(const bf16x8*)&Vs[db * 16 + l16][g4 * 8];
      oacc[db] = __builtin_amdgcn_mfma_f32_16x16x32_bf16(pfrag, vfrag, oacc[db], 0, 0, 0);
    }
  }

  // reduce l over the 16 lanes holding each row's columns (once, at the end)
#pragma unroll
  for (int r = 0; r < 4; ++r) {
#pragma unroll
    for (int off = 1; off < 16; off <<= 1)
      lacc[r] += __shfl_xor(lacc[r], off, 64);
  }
  float invl[4];
#pragma unroll
  for (int r = 0; r < 4; ++r) invl[r] = 1.f / lacc[r];

  // ---- epilogue: O tile -> LDS (normalized bf16), re-fragment, O @ Wo[h*128:+128,:] ----
  __syncthreads();
#pragma unroll
  for (int db = 0; db < 8; ++db) {
#pragma unroll
    for (int r = 0; r < 4; ++r)
      Uni[(w * 16 + g4 * 4 + r) * 136 + db * 16 + l16] = f2b(oacc[db][r] * invl[r]);
  }
  __syncthreads();
  bf16x8 a2[4];
#pragma unroll
  for (int kc = 0; kc < 4; ++kc)
    a2[kc] = *(const bf16x8*)&Uni[(w * 16 + l16) * 136 + kc * 32 + g4 * 8];
  f32x4 acc2[8];
#pragma unroll
  for (int nb = 0; nb < 8; ++nb) acc2[nb] = fz;
#pragma unroll
  for (int kc = 0; kc < 4; ++kc) {
#pragma unroll
    for (int nb = 0; nb < 8; ++nb) {
      bf16x8 b2v = *(const bf16x8*)(Wot + (size_t)(nb * 16 + l16) * 4096 + h * 128 + kc * 32 + g4 * 8);
      acc2[nb] = __builtin_amdgcn_mfma_f32_16x16x32_bf16(a2[kc], b2v, acc2[nb], 0, 0, 0);
    }
  }
#pragma unroll
  for (int nb = 0; nb < 8; ++nb) {
#pragma unroll
    for (int r = 0; r < 4; ++r)
      atomicAdd(&out[(size_t)(qi0 + w * 16 + g4 * 4 + r) * 128 + nb * 16 + l16], acc2[nb][r]);
  }
}

extern "C" void kernel_launch(void* const* d_in, const int* in_sizes, int n_in,
                              void* d_out, int out_size, void* d_ws, size_t ws_size,
                              hipStream_t stream) {
  const float* query  = (const float*)d_in[0];
  const float* keys   = (const float*)d_in[1];
  const float* values = (const float*)d_in[2];
  const float* Wq = (const float*)d_in[3];
  const float* bq = (const float*)d_in[4];
  const float* Wk = (const float*)d_in[5];
  const float* bk = (const float*)d_in[6];
  const float* Wv = (const float*)d_in[7];
  const float* bv = (const float*)d_in[8];
  const float* Wo = (const float*)d_in[9];
  const float* bo = (const float*)d_in[10];
  float* out = (float*)d_out;
  char* ws = (char*)d_ws;
  const size_t MB = 1024 * 1024;
  const size_t NEEDED = 10 * MB + 512 * 1024;
  if (ws_size < NEEDED) {  // diagnostic sentinel: absmax 12345 => ws too small
    ws_marker<<<1024, 256, 0, stream>>>(out);
    return;
  }
  unsigned short* Wqb   = (unsigned short*)(ws);                        // 1 MiB   [128][4096]
  unsigned short* Wkt   = (unsigned short*)(ws + 1 * MB);               // 256 KiB [1024][128]
  unsigned short* Wvt   = (unsigned short*)(ws + 1 * MB + 256 * 1024);  // 256 KiB
  unsigned short* Wot   = (unsigned short*)(ws + 1 * MB + 512 * 1024);  // 1 MiB   [128][4096]
  unsigned short* kproj = (unsigned short*)(ws + 2 * MB + 512 * 1024);  // 4 MiB
  unsigned short* vproj = (unsigned short*)(ws + 6 * MB + 512 * 1024);  // 4 MiB -> ends 10.5 MB

  cast_w<<<2048, 256, 0, stream>>>(Wq, Wqb, 128 * 4096);
  transpose_w<<<512, 256, 0, stream>>>(Wk, Wkt, 128, 1024);
  transpose_w<<<512, 256, 0, stream>>>(Wv, Wvt, 128, 1024);
  transpose_w<<<2048, 256, 0, stream>>>(Wo, Wot, 4096, 128);

  proj_gemm<<<dim3(16, 32), 256, 0, stream>>>(keys,   Wkt, bk, kproj, 1024);
  proj_gemm<<<dim3(16, 32), 256, 0, stream>>>(values, Wvt, bv, vproj, 1024);

  rope_kv<<<4096, 256, 0, stream>>>(kproj, vproj);

  init_out<<<1024, 256, 0, stream>>>(bo, out);

  attn_fused<<<dim3(32, 32), 256, 0, stream>>>(query, Wqb, bq, kproj, vproj, Wot, out);
}

// Round 8
// 214.458 us; speedup vs baseline: 4.7811x; 4.7811x over previous
//
#include <hip/hip_runtime.h>
#include <math.h>

// GQA B=1 S=2048 D=128 H=32 KVH=8. d_out f32. ws 10.5MB (small) / 26.5MB (big).
// Round 8: fix V^T projection write to honor the (B,S,KVH*D)->(B,KVH,S,D) view
// scramble: v[g][s][d] = Vproj[g*256 + (s>>3)][(s&7)*128 + d]. Round 7 wrote the
// unscrambled mapping -> decorrelated output. RoPE trig back to f64 (r6-proven);
// same-wave LDS write->read barriers restored (Ps, Otile).

#define SCALE 0.08838834764831843f  // 1/sqrt(128)

typedef short bf16x8 __attribute__((ext_vector_type(8)));
typedef float f32x4 __attribute__((ext_vector_type(4)));

__device__ __forceinline__ unsigned short f2b(float f) {
  union { float f; unsigned u; } x; x.f = f;
  return (unsigned short)((x.u + 0x7FFFu + ((x.u >> 16) & 1u)) >> 16);
}
__device__ __forceinline__ float b2f(unsigned short b) {
  union { unsigned u; float f; } x; x.u = ((unsigned)b) << 16;
  return x.f;
}
__device__ __forceinline__ void lds_dma16(void* lds, const void* g) {
  __builtin_amdgcn_global_load_lds(
      (const __attribute__((address_space(1))) unsigned int*)g,
      (__attribute__((address_space(3))) unsigned int*)lds, 16, 0, 0);
}

__global__ void cast_w(const float* __restrict__ W, unsigned short* __restrict__ Wb, int n) {
  int i = blockIdx.x * 256 + threadIdx.x;
  if (i < n) Wb[i] = f2b(W[i]);
}

// Wt[n][k] = bf16(W[k][n])
__global__ void transpose_w(const float* __restrict__ W, unsigned short* __restrict__ Wt,
                            int K, int N) {
  int idx = blockIdx.x * 256 + threadIdx.x;
  if (idx >= K * N) return;
  int n = idx / K, k = idx - n * K;
  Wt[idx] = f2b(W[(size_t)k * N + n]);
}

// C = X[2048,128] @ W + bias (Wt[n][k]). MODE 0: row-major bf16 C[2048,N].
// MODE 1 (V): write V^T honoring the view scramble:
//   Vproj[mi][n] == v[g=mi>>8][s=((mi&255)<<3)|(n>>7)][d=n&127]  ->  vt[g][d][s]
template <int MODE>
__global__ __launch_bounds__(256) void proj_gemm(const float* __restrict__ X,
                                                 const unsigned short* __restrict__ Wt,
                                                 const float* __restrict__ bias,
                                                 unsigned short* __restrict__ C, int N) {
  int n0 = blockIdx.x * 64, m0 = blockIdx.y * 64;
  int tid = threadIdx.x;
  int w = tid >> 6, l = tid & 63;
  int l16 = l & 15, g4 = l >> 4;
  int arow = m0 + w * 16 + l16;
  f32x4 acc[4];
  const f32x4 fz = {0.f, 0.f, 0.f, 0.f};
#pragma unroll
  for (int nb = 0; nb < 4; ++nb) acc[nb] = fz;
#pragma unroll
  for (int kc = 0; kc < 4; ++kc) {
    int kbase = kc * 32 + g4 * 8;
    const float* xp = X + (size_t)arow * 128 + kbase;
    bf16x8 a;
#pragma unroll
    for (int j = 0; j < 8; ++j) a[j] = (short)f2b(xp[j]);
#pragma unroll
    for (int nb = 0; nb < 4; ++nb) {
      bf16x8 b = *(const bf16x8*)(Wt + (size_t)(n0 + nb * 16 + l16) * 128 + kbase);
      acc[nb] = __builtin_amdgcn_mfma_f32_16x16x32_bf16(a, b, acc[nb], 0, 0, 0);
    }
  }
#pragma unroll
  for (int nb = 0; nb < 4; ++nb) {
    int n = n0 + nb * 16 + l16;
    float bv = bias[n];
#pragma unroll
    for (int r = 0; r < 4; ++r) {
      int mi = m0 + w * 16 + g4 * 4 + r;
      unsigned short v = f2b(acc[nb][r] + bv);
      if (MODE == 0) {
        C[(size_t)mi * N + n] = v;
      } else {
        int g = mi >> 8;
        int s = ((mi & 255) << 3) | (n >> 7);
        int d = n & 127;
        C[(size_t)g * 262144 + (size_t)d * 2048 + s] = v;
      }
    }
  }
}

// RoPE in place on K flat buffer (flat == (g,t,d) view, identity on reshape)
__global__ void rope_k(unsigned short* __restrict__ kp) {
  int idx = blockIdx.x * 256 + threadIdx.x;  // 8*2048*64
  int d2 = idx & 63;
  int t = (idx >> 6) & 2047;
  int g = idx >> 17;
  size_t base = ((size_t)g * 2048 + t) * 128;
  double invf = pow(10000.0, -(double)d2 / 64.0);
  float ang = (float)((double)t * invf);
  float cf = (float)cos((double)ang);
  float sf = (float)sin((double)ang);
  float x1 = b2f(kp[base + d2]), x2 = b2f(kp[base + 64 + d2]);
  kp[base + d2] = f2b(x1 * cf - x2 * sf);
  kp[base + 64 + d2] = f2b(x2 * cf + x1 * sf);
}

// RoPE in place on V^T (g,d,t): thread owns rows d2 and d2+64 at column t
__global__ void rope_vt(unsigned short* __restrict__ vt) {
  int idx = blockIdx.x * 256 + threadIdx.x;  // 8*64*2048
  int t = idx & 2047;
  int d2 = (idx >> 11) & 63;
  int g = idx >> 17;
  size_t b1 = (size_t)g * 262144 + (size_t)d2 * 2048 + t;
  size_t b2i = b1 + 64 * 2048;
  double invf = pow(10000.0, -(double)d2 / 64.0);
  float ang = (float)((double)t * invf);
  float cf = (float)cos((double)ang);
  float sf = (float)sin((double)ang);
  float y1 = b2f(vt[b1]), y2 = b2f(vt[b2i]);
  vt[b1] = f2b(y1 * cf - y2 * sf);
  vt[b2i] = f2b(y2 * cf + y1 * sf);
}

__global__ void init_out(const float* __restrict__ bo, float* __restrict__ out) {
  int idx = blockIdx.x * 256 + threadIdx.x;
  out[idx] = bo[idx & 127];
}

__global__ void ws_marker(float* __restrict__ out) {
  out[blockIdx.x * 256 + threadIdx.x] = 12345.0f;
}

// LDS map (bytes): K[2][32][128]sh @0 (2x8KB, chunk-XOR swizzled)
//                  V^T[2][128][32]sh @16384 (2x8KB, linear)
//                  Ps[4][16][40]sh @32768 (5120B)   total 37888
template <int FUSED_Q>
__global__ __launch_bounds__(256, 4) void attn_kernel(
    const float* __restrict__ X, const unsigned short* __restrict__ Wqb,
    const float* __restrict__ bq, const unsigned short* __restrict__ qp,
    const unsigned short* __restrict__ kp, const unsigned short* __restrict__ vt,
    const unsigned short* __restrict__ Wot, float* __restrict__ out) {
  __shared__ __align__(16) char smem[37888];
  int bid = blockIdx.x;
  int h = bid & 31, g = h & 7;
  int qi0 = (bid >> 5) * 64;
  int tid = threadIdx.x;
  int w = tid >> 6, l = tid & 63;
  int l16 = l & 15, g4 = l >> 4;

  const f32x4 fz = {0.f, 0.f, 0.f, 0.f};
  bf16x8 qfrag[4];

  if (FUSED_Q) {
    // phase 0: Q rows of head h, qblock == C rows {r0, r0+1} (view scramble)
    unsigned short* Uni = (unsigned short*)smem;  // 8192 shorts
    int r0 = h * 64 + (qi0 >> 5);
    int col0 = tid * 16;
#pragma unroll
    for (int j = 0; j < 2; ++j) {
      const float* xrow = X + (size_t)(r0 + j) * 128;
      float acc[16];
#pragma unroll
      for (int cc = 0; cc < 16; ++cc) acc[cc] = bq[col0 + cc];
      for (int k = 0; k < 128; ++k) {
        float xv = xrow[k];
        bf16x8 w0 = *(const bf16x8*)(Wqb + (size_t)k * 4096 + col0);
        bf16x8 w1 = *(const bf16x8*)(Wqb + (size_t)k * 4096 + col0 + 8);
#pragma unroll
        for (int e = 0; e < 8; ++e) {
          acc[e] += xv * b2f((unsigned short)w0[e]);
          acc[8 + e] += xv * b2f((unsigned short)w1[e]);
        }
      }
#pragma unroll
      for (int cc = 0; cc < 16; ++cc) Uni[j * 4096 + col0 + cc] = f2b(acc[cc]);
    }
    __syncthreads();
    int srow = w * 16 + l16;
    int sj = srow >> 5, scol = (srow & 31) * 128;
#pragma unroll
    for (int kc = 0; kc < 4; ++kc)
      qfrag[kc] = *(const bf16x8*)&Uni[sj * 4096 + scol + kc * 32 + g4 * 8];
    __syncthreads();  // all Uni reads done before DMA overwrites it
  } else {
    const unsigned short* qrow = qp + ((size_t)h * 2048 + qi0 + w * 16 + l16) * 128;
#pragma unroll
    for (int kc = 0; kc < 4; ++kc)
      qfrag[kc] = *(const bf16x8*)(qrow + kc * 32 + g4 * 8);
  }

  const char* kg = (const char*)(kp + (size_t)g * 262144);
  const char* vg = (const char*)(vt + (size_t)g * 262144);
  unsigned short* PsW = (unsigned short*)(smem + 32768) + w * 640;

  // prologue: DMA tile 0 into buffer 0 (K swizzled-source, V linear)
#pragma unroll
  for (int i = 0; i < 2; ++i) {
    int off = w * 2048 + i * 1024 + l * 16;
    int row = off >> 8, ch = (off >> 4) & 15;
    int rch = ch ^ (row & 7);
    lds_dma16(smem + w * 2048 + i * 1024, kg + (size_t)row * 256 + rch * 16);
    int vrow = off >> 6, vcb = off & 63;
    lds_dma16(smem + 16384 + w * 2048 + i * 1024, vg + (size_t)vrow * 4096 + vcb);
  }
  __syncthreads();

  f32x4 oacc[8];
#pragma unroll
  for (int db = 0; db < 8; ++db) oacc[db] = fz;
  float lacc[4] = {0.f, 0.f, 0.f, 0.f};

  int c = 0;
  for (int t = 0; t < 64; ++t) {
    if (t < 63) {  // prefetch t+1 into buffer c^1
      int tn = t + 1;
#pragma unroll
      for (int i = 0; i < 2; ++i) {
        int off = w * 2048 + i * 1024 + l * 16;
        int row = off >> 8, ch = (off >> 4) & 15;
        int rch = ch ^ (row & 7);
        lds_dma16(smem + (c ^ 1) * 8192 + w * 2048 + i * 1024,
                  kg + (size_t)tn * 8192 + (size_t)row * 256 + rch * 16);
        int vrow = off >> 6, vcb = off & 63;
        lds_dma16(smem + 16384 + (c ^ 1) * 8192 + w * 2048 + i * 1024,
                  vg + (size_t)vrow * 4096 + (size_t)tn * 64 + vcb);
      }
    }

    // QK^T: S[16q x 32kv] per wave from swizzled K buffer
    f32x4 sacc[2];
    sacc[0] = fz; sacc[1] = fz;
#pragma unroll
    for (int kc = 0; kc < 4; ++kc) {
#pragma unroll
      for (int jb = 0; jb < 2; ++jb) {
        int krow = jb * 16 + l16;
        int rch = (kc * 4 + g4) ^ (krow & 7);
        bf16x8 bfrag = *(const bf16x8*)(smem + c * 8192 + krow * 256 + rch * 16);
        sacc[jb] = __builtin_amdgcn_mfma_f32_16x16x32_bf16(qfrag[kc], bfrag, sacc[jb], 0, 0, 0);
      }
    }
    // direct-exp softmax (|s*SCALE| small; shift-invariant)
#pragma unroll
    for (int r = 0; r < 4; ++r) {
      unsigned short u0 = f2b(__expf(sacc[0][r] * SCALE));
      unsigned short u1 = f2b(__expf(sacc[1][r] * SCALE));
      lacc[r] += b2f(u0) + b2f(u1);
      PsW[(g4 * 4 + r) * 40 + l16] = u0;
      PsW[(g4 * 4 + r) * 40 + 16 + l16] = u1;
    }
    __syncthreads();  // Ps visible (also drains this iter's prefetch DMA)
    bf16x8 pfrag = *(const bf16x8*)(PsW + l16 * 40 + g4 * 8);
#pragma unroll
    for (int db = 0; db < 8; ++db) {
      bf16x8 vfrag = *(const bf16x8*)(smem + 16384 + c * 8192 + (db * 16 + l16) * 64 + g4 * 16);
      oacc[db] = __builtin_amdgcn_mfma_f32_16x16x32_bf16(pfrag, vfrag, oacc[db], 0, 0, 0);
    }
    __syncthreads();  // all reads of buffer c done before next iter's DMA
    c ^= 1;
  }

  // denominator: reduce over the 16 lanes holding each row's columns
#pragma unroll
  for (int r = 0; r < 4; ++r) {
#pragma unroll
    for (int off = 1; off < 16; off <<= 1)
      lacc[r] += __shfl_xor(lacc[r], off, 64);
  }
  float invl[4];
#pragma unroll
  for (int r = 0; r < 4; ++r) invl[r] = 1.f / lacc[r];

  // epilogue: O tile -> LDS bf16, re-fragment, O @ Wo[h*128:+128,:] -> atomicAdd
  unsigned short* Otile = (unsigned short*)smem;  // [64][136]
#pragma unroll
  for (int db = 0; db < 8; ++db) {
#pragma unroll
    for (int r = 0; r < 4; ++r)
      Otile[(w * 16 + g4 * 4 + r) * 136 + db * 16 + l16] = f2b(oacc[db][r] * invl[r]);
  }
  __syncthreads();
  bf16x8 a2[4];
#pragma unroll
  for (int kc = 0; kc < 4; ++kc)
    a2[kc] = *(const bf16x8*)&Otile[(w * 16 + l16) * 136 + kc * 32 + g4 * 8];
  f32x4 acc2[8];
#pragma unroll
  for (int nb = 0; nb < 8; ++nb) acc2[nb] = fz;
#pragma unroll
  for (int kc = 0; kc < 4; ++kc) {
#pragma unroll
    for (int nb = 0; nb < 8; ++nb) {
      bf16x8 b2v = *(const bf16x8*)(Wot + (size_t)(nb * 16 + l16) * 4096 + h * 128 + kc * 32 + g4 * 8);
      acc2[nb] = __builtin_amdgcn_mfma_f32_16x16x32_bf16(a2[kc], b2v, acc2[nb], 0, 0, 0);
    }
  }
#pragma unroll
  for (int nb = 0; nb < 8; ++nb) {
#pragma unroll
    for (int r = 0; r < 4; ++r)
      atomicAdd(&out[(size_t)(qi0 + w * 16 + g4 * 4 + r) * 128 + nb * 16 + l16], acc2[nb][r]);
  }
}

extern "C" void kernel_launch(void* const* d_in, const int* in_sizes, int n_in,
                              void* d_out, int out_size, void* d_ws, size_t ws_size,
                              hipStream_t stream) {
  const float* query  = (const float*)d_in[0];
  const float* keys   = (const float*)d_in[1];
  const float* values = (const float*)d_in[2];
  const float* Wq = (const float*)d_in[3];
  const float* bq = (const float*)d_in[4];
  const float* Wk = (const float*)d_in[5];
  const float* bk = (const float*)d_in[6];
  const float* Wv = (const float*)d_in[7];
  const float* bv = (const float*)d_in[8];
  const float* Wo = (const float*)d_in[9];
  const float* bo = (const float*)d_in[10];
  float* out = (float*)d_out;
  char* ws = (char*)d_ws;
  const size_t MB = 1024 * 1024;
  if (ws_size < 10 * MB + 512 * 1024) {  // sentinel: absmax 12345 => ws too small
    ws_marker<<<1024, 256, 0, stream>>>(out);
    return;
  }
  unsigned short* Wq2   = (unsigned short*)(ws);                        // 1 MiB
  unsigned short* Wkt   = (unsigned short*)(ws + 1 * MB);               // 256 KiB
  unsigned short* Wvt   = (unsigned short*)(ws + 1 * MB + 256 * 1024);  // 256 KiB
  unsigned short* Wot   = (unsigned short*)(ws + 1 * MB + 512 * 1024);  // 1 MiB
  unsigned short* kproj = (unsigned short*)(ws + 2 * MB + 512 * 1024);  // 4 MiB
  unsigned short* vt    = (unsigned short*)(ws + 6 * MB + 512 * 1024);  // 4 MiB -> 10.5 MB
  unsigned short* qproj = (unsigned short*)(ws + 10 * MB + 512 * 1024); // 16 MiB (big path)
  bool big = ws_size >= 27 * MB;

  transpose_w<<<512, 256, 0, stream>>>(Wk, Wkt, 128, 1024);
  transpose_w<<<512, 256, 0, stream>>>(Wv, Wvt, 128, 1024);
  transpose_w<<<2048, 256, 0, stream>>>(Wo, Wot, 4096, 128);

  proj_gemm<0><<<dim3(16, 32), 256, 0, stream>>>(keys,   Wkt, bk, kproj, 1024);
  proj_gemm<1><<<dim3(16, 32), 256, 0, stream>>>(values, Wvt, bv, vt,    1024);

  rope_k<<<4096, 256, 0, stream>>>(kproj);
  rope_vt<<<4096, 256, 0, stream>>>(vt);

  init_out<<<1024, 256, 0, stream>>>(bo, out);

  if (big) {
    transpose_w<<<2048, 256, 0, stream>>>(Wq, Wq2, 128, 4096);  // Wq^T [4096][128]
    proj_gemm<0><<<dim3(64, 32), 256, 0, stream>>>(query, Wq2, bq, qproj, 4096);
    attn_kernel<0><<<1024, 256, 0, stream>>>(query, Wq2, bq, qproj, kproj, vt, Wot, out);
  } else {
    cast_w<<<2048, 256, 0, stream>>>(Wq, Wq2, 128 * 4096);      // Wq row-major bf16
    attn_kernel<1><<<1024, 256, 0, stream>>>(query, Wq2, bq, nullptr, kproj, vt, Wot, out);
  }
}